// Round 9
// baseline (125.964 us; speedup 1.0000x reference)
//
#include <hip/hip_runtime.h>
#include <hip/hip_bf16.h>

#define B_DIM 32
#define T_DIM 2048
#define D_DIM 1024
#define S_MAXK 32
#define NCHUNK 4
#define TCH 512            // T_DIM / NCHUNK
#define DS  512            // D_DIM / 2 (two d-halves)

// ws layout (bytes):
//   hpart float[4][B][32][D] @ 0        : 16,777,216  (per-chunk partial sums, plain stores)
//   h     float[B][32][D]    @ 16777216 : 4,194,304   (reduced sums)
//   counts uint[B][32]       @ 20971520 : 4,096       (zeroed each call)
//   posneg uint[B][32]       @ 20975616 : 4,096       (zeroed; 0xFFFFFFFF-firstpos, 0=absent)
//   ctrl  {tot,num,done}     @ 20979712 : 256         (zeroed)
#define HPART_OFF 0
#define H_OFF     16777216
#define CNT_OFF   20971520
#define PNEG_OFF  20975616
#define CTRL_OFF  20979712
#define ZERO_OFF  CNT_OFF
#define ZERO_LEN  (4096 + 4096 + 256)

#define SLICE_F4  262144   // float4s per hpart chunk slice (B*32*D/4)

// Sequential-scan binning: block = (b, t-chunk, d-half). Thread owns a float2
// column; t iterated linearly, 8-deep named-register load batches; |v| added
// into LDS acc[step][col] (wave-uniform step -> non-atomic RMW). Flush =
// plain coalesced stores to this block's private hpart slice. No fp atomics.
__global__ __launch_bounds__(256) void k_seq(const float* __restrict__ x,
                                             const int* __restrict__ sid,
                                             float* __restrict__ hpart,
                                             unsigned* __restrict__ counts,
                                             unsigned* __restrict__ posneg) {
    __shared__ float acc[S_MAXK * DS];   // 64 KB
    __shared__ int   sc[TCH];            // 2 KB

    const int blk = blockIdx.x;
    const int b   = blk >> 3;
    const int c   = (blk >> 1) & (NCHUNK - 1);
    const int sl  = blk & 1;
    const int tid = threadIdx.x;

    float4* az = (float4*)acc;
    #pragma unroll
    for (int i = tid; i < S_MAXK * DS / 4; i += 256)
        az[i] = make_float4(0.f, 0.f, 0.f, 0.f);
    #pragma unroll
    for (int i = tid; i < TCH; i += 256)
        sc[i] = sid[b * T_DIM + c * TCH + i];
    __syncthreads();

    // counts + first-pos for this chunk (d-half 0 only; 32 lanes)
    if (sl == 0 && tid < 32) {
        int cnt = 0, first = -1;
        for (int t = 0; t < TCH; ++t) {
            if (sc[t] == tid + 1) { cnt++; if (first < 0) first = t; }
        }
        if (cnt) {
            atomicAdd(&counts[(b << 5) + tid], (unsigned)cnt);
            atomicMax(&posneg[(b << 5) + tid],
                      0xFFFFFFFFu - (unsigned)(c * TCH + first));
        }
    }

    const float2* xp = (const float2*)(x + (size_t)b * T_DIM * D_DIM
                                         + (size_t)c * TCH * D_DIM + sl * DS);
    float2* accp = (float2*)acc;         // bin stride DS/2 = 256 float2

    for (int t = 0; t < TCH; t += 8) {
        float2 v0 = xp[(size_t)(t + 0) * (D_DIM / 2) + tid];
        float2 v1 = xp[(size_t)(t + 1) * (D_DIM / 2) + tid];
        float2 v2 = xp[(size_t)(t + 2) * (D_DIM / 2) + tid];
        float2 v3 = xp[(size_t)(t + 3) * (D_DIM / 2) + tid];
        float2 v4 = xp[(size_t)(t + 4) * (D_DIM / 2) + tid];
        float2 v5 = xp[(size_t)(t + 5) * (D_DIM / 2) + tid];
        float2 v6 = xp[(size_t)(t + 6) * (D_DIM / 2) + tid];
        float2 v7 = xp[(size_t)(t + 7) * (D_DIM / 2) + tid];
        int s0 = sc[t + 0], s1 = sc[t + 1], s2 = sc[t + 2], s3 = sc[t + 3];
        int s4 = sc[t + 4], s5 = sc[t + 5], s6 = sc[t + 6], s7 = sc[t + 7];
        if (s0) { float2 a = accp[(s0 - 1) * 256 + tid];
                  a.x += fabsf(v0.x); a.y += fabsf(v0.y);
                  accp[(s0 - 1) * 256 + tid] = a; }
        if (s1) { float2 a = accp[(s1 - 1) * 256 + tid];
                  a.x += fabsf(v1.x); a.y += fabsf(v1.y);
                  accp[(s1 - 1) * 256 + tid] = a; }
        if (s2) { float2 a = accp[(s2 - 1) * 256 + tid];
                  a.x += fabsf(v2.x); a.y += fabsf(v2.y);
                  accp[(s2 - 1) * 256 + tid] = a; }
        if (s3) { float2 a = accp[(s3 - 1) * 256 + tid];
                  a.x += fabsf(v3.x); a.y += fabsf(v3.y);
                  accp[(s3 - 1) * 256 + tid] = a; }
        if (s4) { float2 a = accp[(s4 - 1) * 256 + tid];
                  a.x += fabsf(v4.x); a.y += fabsf(v4.y);
                  accp[(s4 - 1) * 256 + tid] = a; }
        if (s5) { float2 a = accp[(s5 - 1) * 256 + tid];
                  a.x += fabsf(v5.x); a.y += fabsf(v5.y);
                  accp[(s5 - 1) * 256 + tid] = a; }
        if (s6) { float2 a = accp[(s6 - 1) * 256 + tid];
                  a.x += fabsf(v6.x); a.y += fabsf(v6.y);
                  accp[(s6 - 1) * 256 + tid] = a; }
        if (s7) { float2 a = accp[(s7 - 1) * 256 + tid];
                  a.x += fabsf(v7.x); a.y += fabsf(v7.y);
                  accp[(s7 - 1) * 256 + tid] = a; }
    }
    __syncthreads();

    // flush 64 KB to this block's private slice: plain coalesced float4 stores
    float4* hb = (float4*)(hpart + (size_t)c * (B_DIM * S_MAXK * D_DIM)
                                 + (size_t)(b << 5) * D_DIM + sl * DS);
    #pragma unroll
    for (int i = tid; i < S_MAXK * DS / 4; i += 256) {
        int s  = i >> 7;            // / (DS/4)
        int d4 = i & (DS / 4 - 1);
        hb[(size_t)s * (D_DIM / 4) + d4] = az[i];
    }
}

// Sum the 4 chunk slices -> h. All indices in float4 units.
// h = 262,144 float4; 256 blocks x 1024 float4/block; slice stride 262,144.
__global__ __launch_bounds__(256) void k_reduce(const float* __restrict__ hpart,
                                                float* __restrict__ h) {
    const float4* hp = (const float4*)hpart;
    float4* ho = (float4*)h;
    const int base = blockIdx.x * 1024;          // float4 index
    #pragma unroll
    for (int j = 0; j < 4; ++j) {
        int idx = base + j * 256 + threadIdx.x;
        float4 a = hp[idx];
        float4 b = hp[idx + SLICE_F4];
        float4 c = hp[idx + 2 * SLICE_F4];
        float4 d = hp[idx + 3 * SLICE_F4];
        ho[idx] = make_float4(a.x + b.x + c.x + d.x, a.y + b.y + c.y + d.y,
                              a.z + b.z + c.z + d.z, a.w + b.w + c.w + d.w);
    }
}

// One block per b: argsort pos, pairwise E (sums * 1/count), per-b loss;
// atomic-accumulate into ctrl; last block writes out = tot/(num+1e-9).
__global__ __launch_bounds__(256) void k_pairs(const float* __restrict__ h,
                                               const unsigned* __restrict__ counts,
                                               const unsigned* __restrict__ posneg,
                                               const int* __restrict__ labels,
                                               float* __restrict__ ctrl,
                                               float* __restrict__ out) {
    const int b = blockIdx.x;
    const int tid = threadIdx.x;
    __shared__ unsigned posl[32];
    __shared__ float    rcp[32];
    __shared__ int      ordl[32];
    __shared__ float    El[31];

    if (tid < 32) {
        posl[tid] = 0xFFFFFFFFu - posneg[(b << 5) + tid];  // absent -> 0xFFFFFFFF
        unsigned cc = counts[(b << 5) + tid];
        rcp[tid] = 1.0f / (float)(cc > 1u ? cc : 1u);
    }
    __syncthreads();
    if (tid < 32) {                         // stable argsort of pos
        unsigned ps = posl[tid];
        int rk = 0;
        for (int j = 0; j < 32; ++j) {
            unsigned pj = posl[j];
            if (pj < ps || (pj == ps && j < tid)) rk++;
        }
        ordl[rk] = tid;
    }
    __syncthreads();

    const int wave = tid >> 6;
    const int lane = tid & 63;
    for (int p = wave; p < 31; p += 4) {
        int A  = ordl[p];
        int B2 = ordl[p + 1];
        float ssum = 0.0f;
        if (posl[B2] < (unsigned)T_DIM) {
            const float* pa = &h[((size_t)(b << 5) + A)  * D_DIM];
            const float* pb = &h[((size_t)(b << 5) + B2) * D_DIM];
            float ra = rcp[A], rb = rcp[B2];
            for (int d = lane * 4; d < D_DIM; d += 256) {
                float4 a4 = *(const float4*)(pa + d);
                float4 b4 = *(const float4*)(pb + d);
                float d0 = fmaxf(a4.x * ra - b4.x * rb, 0.f);
                float d1 = fmaxf(a4.y * ra - b4.y * rb, 0.f);
                float d2 = fmaxf(a4.z * ra - b4.z * rb, 0.f);
                float d3 = fmaxf(a4.w * ra - b4.w * rb, 0.f);
                ssum += d0 * d0 + d1 * d1 + d2 * d2 + d3 * d3;
            }
        }
        #pragma unroll
        for (int off = 32; off; off >>= 1) ssum += __shfl_down(ssum, off);
        if (lane == 0) El[p] = ssum * (1.0f / D_DIM);
    }
    __syncthreads();

    if (tid == 0) {
        float lpos = 0.f, lneg = 0.f;
        int np = 0, ni = 0, nn = 0;
        for (int s2 = 0; s2 < 32; ++s2) nn += (posl[s2] < (unsigned)T_DIM) ? 1 : 0;
        for (int p = 0; p < 31; ++p) {
            int A  = ordl[p];
            int B2 = ordl[p + 1];
            if (posl[B2] < (unsigned)T_DIM) {    // pair_valid
                float Ev = El[p];
                np++; lpos += Ev;
                if (A > B2) { ni++; lneg += fmaxf(1.0f - Ev, 0.0f); }  // ALPHA=1
            }
        }
        float loss_pos = lpos / (float)(np > 1 ? np : 1);
        float loss_neg = lneg / (float)(ni > 1 ? ni : 1);
        int lab = labels[b];
        bool pc = (lab == 1) && (nn >= 2);
        bool nc = (lab == 0) && (ni > 0);
        float contrib = (pc ? loss_pos : 0.0f) + (nc ? loss_neg : 0.0f);
        float cf = (float)((pc ? 1 : 0) + (nc ? 1 : 0));

        atomicAdd(&ctrl[0], contrib);
        atomicAdd(&ctrl[1], cf);
        __threadfence();
        unsigned old = atomicAdd(&((unsigned*)ctrl)[2], 1u);
        if (old == (unsigned)(B_DIM - 1)) {      // last block overall
            __threadfence();
            float tot = atomicAdd(&ctrl[0], 0.0f);   // coherent reads
            float num = atomicAdd(&ctrl[1], 0.0f);
            out[0] = tot / (num + 1e-9f);
        }
    }
}

extern "C" void kernel_launch(void* const* d_in, const int* in_sizes, int n_in,
                              void* d_out, int out_size, void* d_ws, size_t ws_size,
                              hipStream_t stream) {
    const float* x      = (const float*)d_in[0];
    const int*   sid    = (const int*)d_in[1];
    const int*   labels = (const int*)d_in[2];
    float* out = (float*)d_out;
    char*  ws  = (char*)d_ws;

    float*    hpart  = (float*)(ws + HPART_OFF);
    float*    h      = (float*)(ws + H_OFF);
    unsigned* counts = (unsigned*)(ws + CNT_OFF);
    unsigned* posneg = (unsigned*)(ws + PNEG_OFF);
    float*    ctrl   = (float*)(ws + CTRL_OFF);

    hipMemsetAsync(ws + ZERO_OFF, 0, ZERO_LEN, stream);   // counts+posneg+ctrl only

    k_seq   <<<B_DIM * NCHUNK * 2, 256, 0, stream>>>(x, sid, hpart, counts, posneg);
    k_reduce<<<256,                256, 0, stream>>>(hpart, h);
    k_pairs <<<B_DIM,              256, 0, stream>>>(h, counts, posneg, labels, ctrl, out);
}

// Round 10
// 69.985 us; speedup vs baseline: 1.7999x; 1.7999x over previous
//
#include <hip/hip_runtime.h>
#include <hip/hip_bf16.h>

#define B_DIM 32
#define T_DIM 2048
#define D_DIM 1024
#define S_MAXK 32

// ws layout (bytes):
//   h      float[B][32][D]   @ 0        : 4,194,304   (already divided by count)
//   counts uint [B][32]      @ 4194304  : 4,096
//   res    float[B][2]       @ 4198400  : 256
//   pos    uint [B][32]      @ 4198656  : 4,096
#define H_OFF      0
#define COUNTS_OFF 4194304
#define RES_OFF    4198400
#define POS_OFF    4198656

// One block per (b, step). Scan sid row -> match list in LDS (no global
// atomics), then register-accumulate |x| over matching rows, 4-deep batched
// loads for memory-level parallelism. Each x row is read by exactly one block.
__global__ __launch_bounds__(256) void k_gather(const float* __restrict__ x,
                                                const int* __restrict__ sid,
                                                float* __restrict__ h,
                                                unsigned* __restrict__ counts,
                                                unsigned* __restrict__ pos) {
    __shared__ int      list[T_DIM];
    __shared__ int      cnt;
    __shared__ unsigned firstpos;

    const int b = blockIdx.x >> 5;        // blocks with same b adjacent (sid L2 reuse)
    const int s = blockIdx.x & 31;        // step value = s+1
    const int tid = threadIdx.x;

    if (tid == 0) { cnt = 0; firstpos = 0xFFFFFFFFu; }
    __syncthreads();

    const int* srow = sid + b * T_DIM;
    unsigned myfirst = 0xFFFFFFFFu;
    for (int t = tid; t < T_DIM; t += 256) {
        if (srow[t] == s + 1) {
            int idx = atomicAdd(&cnt, 1);   // LDS atomic, tiny traffic
            list[idx] = t;
            if ((unsigned)t < myfirst) myfirst = (unsigned)t;
        }
    }
    if (myfirst != 0xFFFFFFFFu) atomicMin(&firstpos, myfirst);
    __syncthreads();

    const int n = cnt;
    const float4* xb = (const float4*)(x + (size_t)b * T_DIM * D_DIM);
    const int dcol = tid;                  // float4 column: d = tid*4
    float4 acc = {0.f, 0.f, 0.f, 0.f};

    int i = 0;
    for (; i + 4 <= n; i += 4) {
        int t0 = list[i], t1 = list[i + 1], t2 = list[i + 2], t3 = list[i + 3];
        float4 v0 = xb[(size_t)t0 * (D_DIM / 4) + dcol];
        float4 v1 = xb[(size_t)t1 * (D_DIM / 4) + dcol];
        float4 v2 = xb[(size_t)t2 * (D_DIM / 4) + dcol];
        float4 v3 = xb[(size_t)t3 * (D_DIM / 4) + dcol];
        acc.x += fabsf(v0.x) + fabsf(v1.x) + fabsf(v2.x) + fabsf(v3.x);
        acc.y += fabsf(v0.y) + fabsf(v1.y) + fabsf(v2.y) + fabsf(v3.y);
        acc.z += fabsf(v0.z) + fabsf(v1.z) + fabsf(v2.z) + fabsf(v3.z);
        acc.w += fabsf(v0.w) + fabsf(v1.w) + fabsf(v2.w) + fabsf(v3.w);
    }
    for (; i < n; ++i) {
        float4 v = xb[(size_t)list[i] * (D_DIM / 4) + dcol];
        acc.x += fabsf(v.x); acc.y += fabsf(v.y);
        acc.z += fabsf(v.z); acc.w += fabsf(v.w);
    }

    const float r = 1.0f / (float)(n > 1 ? n : 1);
    float4 out4 = {acc.x * r, acc.y * r, acc.z * r, acc.w * r};
    ((float4*)(h + ((size_t)b * 32 + s) * D_DIM))[dcol] = out4;

    if (tid == 0) {
        counts[b * 32 + s] = (unsigned)n;
        pos[b * 32 + s] = (n > 0) ? firstpos : (unsigned)T_DIM;
    }
}

__global__ __launch_bounds__(256) void k_pairs(const float* __restrict__ h,
                                               const unsigned* __restrict__ counts,
                                               const unsigned* __restrict__ pos,
                                               const int* __restrict__ labels,
                                               float* __restrict__ res) {
    const int b = blockIdx.x;
    const int tid = threadIdx.x;
    __shared__ unsigned posl[32];
    __shared__ int      ordl[32];
    __shared__ float    El[31];

    if (tid < 32) posl[tid] = pos[b * 32 + tid];
    __syncthreads();
    if (tid < 32) {
        unsigned ps = posl[tid];
        int r = 0;
        for (int j = 0; j < 32; ++j) {
            unsigned pj = posl[j];
            if (pj < ps || (pj == ps && j < tid)) r++;
        }
        ordl[r] = tid;   // stable argsort of pos
    }
    __syncthreads();

    const int wave = tid >> 6;
    const int lane = tid & 63;
    for (int i = wave; i < 31; i += 4) {
        int A  = ordl[i];
        int B2 = ordl[i + 1];
        const float* pa = &h[((size_t)b * 32 + A)  * D_DIM];
        const float* pb = &h[((size_t)b * 32 + B2) * D_DIM];
        float ssum = 0.0f;
        for (int d = lane * 4; d < D_DIM; d += 256) {
            float4 a4 = *(const float4*)(pa + d);
            float4 b4 = *(const float4*)(pb + d);
            float d0 = fmaxf(a4.x - b4.x, 0.0f);
            float d1 = fmaxf(a4.y - b4.y, 0.0f);
            float d2 = fmaxf(a4.z - b4.z, 0.0f);
            float d3 = fmaxf(a4.w - b4.w, 0.0f);
            ssum += d0 * d0 + d1 * d1 + d2 * d2 + d3 * d3;
        }
        #pragma unroll
        for (int off = 32; off; off >>= 1) ssum += __shfl_down(ssum, off);
        if (lane == 0) El[i] = ssum * (1.0f / D_DIM);
    }
    __syncthreads();

    if (tid == 0) {
        float lpos = 0.0f, lneg = 0.0f;
        int np = 0, ni = 0, n = 0;
        for (int s2 = 0; s2 < 32; ++s2) n += (posl[s2] < T_DIM) ? 1 : 0;
        for (int i = 0; i < 31; ++i) {
            int A  = ordl[i];
            int B2 = ordl[i + 1];
            if (posl[B2] < T_DIM) {         // pair_valid
                float E = El[i];
                np++; lpos += E;
                if (A > B2) {               // inversion in step order
                    ni++; lneg += fmaxf(1.0f - E, 0.0f);   // ALPHA = 1
                }
            }
        }
        float loss_pos = lpos / (float)(np > 1 ? np : 1);
        float loss_neg = lneg / (float)(ni > 1 ? ni : 1);
        int lab = labels[b];
        bool pc = (lab == 1) && (n >= 2);
        bool nc = (lab == 0) && (ni > 0);
        res[b * 2 + 0] = (pc ? loss_pos : 0.0f) + (nc ? loss_neg : 0.0f);
        res[b * 2 + 1] = (float)((pc ? 1 : 0) + (nc ? 1 : 0));
    }
}

__global__ void k_final(const float* __restrict__ res, float* __restrict__ out) {
    const int lane = threadIdx.x;
    float t = 0.0f, c = 0.0f;
    if (lane < 32) { t = res[lane * 2]; c = res[lane * 2 + 1]; }
    #pragma unroll
    for (int off = 32; off; off >>= 1) {
        t += __shfl_down(t, off);
        c += __shfl_down(c, off);
    }
    if (lane == 0) out[0] = t / (c + 1e-9f);
}

extern "C" void kernel_launch(void* const* d_in, const int* in_sizes, int n_in,
                              void* d_out, int out_size, void* d_ws, size_t ws_size,
                              hipStream_t stream) {
    const float* x      = (const float*)d_in[0];
    const int*   sid    = (const int*)d_in[1];
    const int*   labels = (const int*)d_in[2];
    float* out = (float*)d_out;
    char*  ws  = (char*)d_ws;

    float*    h      = (float*)(ws + H_OFF);
    unsigned* counts = (unsigned*)(ws + COUNTS_OFF);
    float*    res    = (float*)(ws + RES_OFF);
    unsigned* pos    = (unsigned*)(ws + POS_OFF);

    k_gather<<<B_DIM * S_MAXK, 256, 0, stream>>>(x, sid, h, counts, pos);
    k_pairs<<<B_DIM, 256, 0, stream>>>(h, counts, pos, labels, res);
    k_final<<<1, 64, 0, stream>>>(res, out);
}